// Round 2
// baseline (619.716 us; speedup 1.0000x reference)
//
#include <hip/hip_runtime.h>
#include <hip/hip_bf16.h>
#include <math.h>

#define BB 32
#define CC 256
#define HH 64
#define HW 4096

typedef __attribute__((ext_vector_type(8))) short short8;
typedef __attribute__((ext_vector_type(4))) float f32x4;

__device__ __forceinline__ float gelu_erf(float x) {
    return 0.5f * x * (1.0f + erff(x * 0.70710678118654752f));
}

// ---------------- Kernel 0: convert pw weights f32 -> bf16 ----------------
__global__ __launch_bounds__(256) void k_prep(const float* __restrict__ pw,
                                              __hip_bfloat16* __restrict__ pwb)
{
    const int i = blockIdx.x * 256 + threadIdx.x;   // 65536 total
    pwb[i] = __float2bfloat16(pw[i]);
}

// ---------------- Kernel 1: 3 depthwise convs + BN + GELU, averaged ----------------
// one block per (b,c) plane; 70x70 haloed plane in LDS; each thread computes a 4x4 tile
__global__ __launch_bounds__(256) void k_dwconv(
    const float* __restrict__ x,
    const float* __restrict__ w3,
    const float* __restrict__ bn3w, const float* __restrict__ bn3b,
    const float* __restrict__ bn3m, const float* __restrict__ bn3v,
    const float* __restrict__ w5,
    const float* __restrict__ bn5w, const float* __restrict__ bn5b,
    const float* __restrict__ bn5m, const float* __restrict__ bn5v,
    const float* __restrict__ w7,
    const float* __restrict__ bn7w, const float* __restrict__ bn7b,
    const float* __restrict__ bn7m, const float* __restrict__ bn7v,
    __hip_bfloat16* __restrict__ mid)
{
    __shared__ float sm[70 * 70];
    __shared__ float wl[83];
    __shared__ float bnp[6];
    const int tid = threadIdx.x;
    const int blk = blockIdx.x;
    const int c = blk & 255;
    const int b = blk >> 8;
    const float* xp = x + ((size_t)(b * CC + c)) * HW;

    for (int i = tid; i < 4900; i += 256) {
        int r = i / 70, q = i - r * 70;
        int h = r - 3, w = q - 3;
        float v = 0.f;
        if ((unsigned)h < 64u && (unsigned)w < 64u) v = xp[h * 64 + w];
        sm[i] = v;
    }
    if (tid < 9) wl[tid] = w3[c * 9 + tid];
    else if (tid < 34) wl[tid] = w5[c * 25 + tid - 9];
    else if (tid < 83) wl[tid] = w7[c * 49 + tid - 34];
    else if (tid == 83) {
        float s = bn3w[c] * rsqrtf(bn3v[c] + 1e-5f);
        bnp[0] = s; bnp[1] = bn3b[c] - bn3m[c] * s;
    } else if (tid == 84) {
        float s = bn5w[c] * rsqrtf(bn5v[c] + 1e-5f);
        bnp[2] = s; bnp[3] = bn5b[c] - bn5m[c] * s;
    } else if (tid == 85) {
        float s = bn7w[c] * rsqrtf(bn7v[c] + 1e-5f);
        bnp[4] = s; bnp[5] = bn7b[c] - bn7m[c] * s;
    }
    __syncthreads();

    const int ti = tid >> 4, tj = tid & 15;   // 16x16 tiles of 4x4 px
    float a3[16], a5[16], a7[16];
#pragma unroll
    for (int i = 0; i < 16; ++i) { a3[i] = 0.f; a5[i] = 0.f; a7[i] = 0.f; }
    const float* w3l = wl;
    const float* w5l = wl + 9;
    const float* w7l = wl + 34;

#pragma unroll
    for (int pr = 0; pr < 10; ++pr) {
        float r[10];
        const float* srow = &sm[(ti * 4 + pr) * 70 + tj * 4];
#pragma unroll
        for (int q = 0; q < 10; ++q) r[q] = srow[q];
#pragma unroll
        for (int i = 0; i < 4; ++i) {
            const int k7 = pr - i;
            if (k7 >= 0 && k7 <= 6) {
#pragma unroll
                for (int j = 0; j < 4; ++j) {
                    float s = 0.f;
#pragma unroll
                    for (int dx = 0; dx < 7; ++dx) s += r[j + dx] * w7l[k7 * 7 + dx];
                    a7[i * 4 + j] += s;
                }
            }
            const int k5 = pr - 1 - i;
            if (k5 >= 0 && k5 <= 4) {
#pragma unroll
                for (int j = 0; j < 4; ++j) {
                    float s = 0.f;
#pragma unroll
                    for (int dx = 0; dx < 5; ++dx) s += r[j + dx + 1] * w5l[k5 * 5 + dx];
                    a5[i * 4 + j] += s;
                }
            }
            const int k3 = pr - 2 - i;
            if (k3 >= 0 && k3 <= 2) {
#pragma unroll
                for (int j = 0; j < 4; ++j) {
                    float s = 0.f;
#pragma unroll
                    for (int dx = 0; dx < 3; ++dx) s += r[j + dx + 2] * w3l[k3 * 3 + dx];
                    a3[i * 4 + j] += s;
                }
            }
        }
    }

    const float s3 = bnp[0], h3 = bnp[1], s5 = bnp[2], h5 = bnp[3], s7 = bnp[4], h7 = bnp[5];
    __hip_bfloat16* mp = mid + ((size_t)(b * CC + c)) * HW;
#pragma unroll
    for (int i = 0; i < 4; ++i) {
        __hip_bfloat16 o[4];
#pragma unroll
        for (int j = 0; j < 4; ++j) {
            float v = gelu_erf(a3[i * 4 + j] * s3 + h3)
                    + gelu_erf(a5[i * 4 + j] * s5 + h5)
                    + gelu_erf(a7[i * 4 + j] * s7 + h7);
            o[j] = __float2bfloat16(v * (1.0f / 3.0f));
        }
        *(uint2*)&mp[(ti * 4 + i) * 64 + tj * 4] = *(uint2*)o;
    }
}

// ---------------- Kernel 2: pointwise GEMM (MFMA bf16) + pwbn + sumsq ----------------
// block = (b, 64-hw tile) x all 256 output channels; 4 waves, each 16(hw) x 256(o)
#define ASTR 68   // LDS row stride (shorts) for A  [k=32][m=64]
#define BSTR 40   // LDS row stride (shorts) for B  [o=256][k=32]
__global__ __launch_bounds__(256) void k_pw(
    const __hip_bfloat16* __restrict__ mid,
    const __hip_bfloat16* __restrict__ pwb,
    const float* __restrict__ pbw, const float* __restrict__ pbb,
    const float* __restrict__ pbm, const float* __restrict__ pbv,
    __hip_bfloat16* __restrict__ out2,
    float* __restrict__ gx2)
{
    __shared__ __align__(16) short As[32 * ASTR];
    __shared__ __align__(16) short Bs[256 * BSTR];
    __shared__ float sc[256], sh[256], gxp[256];

    const int tid = threadIdx.x;
    const int blk = blockIdx.x;
    const int mt = blk & 63, b = blk >> 6;
    const int hw0 = mt * 64;

    {
        float s = pbw[tid] * rsqrtf(pbv[tid] + 1e-5f);
        sc[tid] = s;
        sh[tid] = pbb[tid] - pbm[tid] * s;
        gxp[tid] = 0.f;
    }

    const int wv = tid >> 6, lane = tid & 63;
    const int qd = lane >> 4, ln16 = lane & 15;

    f32x4 acc[16];
#pragma unroll
    for (int i = 0; i < 16; ++i) acc[i] = (f32x4){0.f, 0.f, 0.f, 0.f};

    const int ak = tid >> 3, am = tid & 7;
    const __hip_bfloat16* aptr = mid + ((size_t)(b * CC + ak)) * HW + hw0 + am * 8;
    const __hip_bfloat16* bptr = pwb + (size_t)tid * 256;

    for (int kk = 0; kk < 8; ++kk) {
        __syncthreads();
        // stage A tile: 32(k) x 64(m), k-major rows
        uint4 av = *(const uint4*)(aptr + (size_t)kk * 32 * HW);
        *(uint2*)&As[ak * ASTR + am * 8]     = make_uint2(av.x, av.y);
        *(uint2*)&As[ak * ASTR + am * 8 + 4] = make_uint2(av.z, av.w);
        // stage B tile: 256(o) x 32(k), row-major (k contiguous)
        const uint4* bp = (const uint4*)(bptr + kk * 32);
#pragma unroll
        for (int j = 0; j < 4; ++j) {
            *(uint4*)&Bs[tid * BSTR + j * 8] = bp[j];
        }
        __syncthreads();

        short8 af;
        const int mloc = wv * 16 + ln16;
#pragma unroll
        for (int j = 0; j < 8; ++j) af[j] = As[(qd * 8 + j) * ASTR + mloc];
#pragma unroll
        for (int nt = 0; nt < 16; ++nt) {
            short8 bf = *(short8*)&Bs[(nt * 16 + ln16) * BSTR + qd * 8];
            acc[nt] = __builtin_amdgcn_mfma_f32_16x16x32_bf16(af, bf, acc[nt], 0, 0, 0);
        }
    }

    // epilogue: pwbn affine, store bf16, per-channel sumsq reduction
    const size_t obase = ((size_t)b * CC) * HW + hw0 + wv * 16 + qd * 4;
#pragma unroll
    for (int nt = 0; nt < 16; ++nt) {
        const int o = nt * 16 + ln16;
        const float s = sc[o], h = sh[o];
        float v0 = acc[nt][0] * s + h;
        float v1 = acc[nt][1] * s + h;
        float v2 = acc[nt][2] * s + h;
        float v3 = acc[nt][3] * s + h;
        float p = v0 * v0 + v1 * v1 + v2 * v2 + v3 * v3;
        p += __shfl_xor(p, 16);
        p += __shfl_xor(p, 32);
        if ((lane & 48) == 0) atomicAdd(&gxp[o], p);
        __hip_bfloat16 ov[4];
        ov[0] = __float2bfloat16(v0);
        ov[1] = __float2bfloat16(v1);
        ov[2] = __float2bfloat16(v2);
        ov[3] = __float2bfloat16(v3);
        *(uint2*)&out2[obase + (size_t)o * HW] = *(uint2*)ov;
    }
    __syncthreads();
    atomicAdd(&gx2[b * CC + tid], gxp[tid]);
}

// ---------------- Kernel 3: GRN Nx = Gx / (mean_c Gx + eps) ----------------
__global__ __launch_bounds__(256) void k_grn(const float* __restrict__ gx2,
                                             float* __restrict__ nx)
{
    const int b = blockIdx.x, t = threadIdx.x;
    const float g = sqrtf(gx2[b * 256 + t]);
    float s = g;
#pragma unroll
    for (int m = 1; m <= 32; m <<= 1) s += __shfl_xor(s, m);
    __shared__ float ws4[4];
    if ((t & 63) == 0) ws4[t >> 6] = s;
    __syncthreads();
    const float tot = ws4[0] + ws4[1] + ws4[2] + ws4[3];
    const float mean = tot * (1.0f / 256.0f);
    nx[b * 256 + t] = g / (mean + 1e-6f);
}

// ---------------- Kernel 4: GRN apply + residual + GELU ----------------
__global__ __launch_bounds__(256) void k_final(
    const __hip_bfloat16* __restrict__ out2,
    const float* __restrict__ x,
    const float* __restrict__ gamma,
    const float* __restrict__ beta,
    const float* __restrict__ nx,
    float* __restrict__ out)
{
    const size_t e = ((size_t)blockIdx.x * 256 + threadIdx.x) * 8;
    const int bc = (int)(e >> 12);
    const int c = bc & 255;
    const float m1 = 1.0f + gamma[c] * nx[bc];
    const float bt = beta[c];

    union { uint4 u; __hip_bfloat16 h[8]; } ov;
    ov.u = *(const uint4*)(out2 + e);
    float4 xa = *(const float4*)(x + e);
    float4 xb = *(const float4*)(x + e + 4);

    float4 ra, rb;
    ra.x = gelu_erf(__bfloat162float(ov.h[0]) * m1 + bt + xa.x);
    ra.y = gelu_erf(__bfloat162float(ov.h[1]) * m1 + bt + xa.y);
    ra.z = gelu_erf(__bfloat162float(ov.h[2]) * m1 + bt + xa.z);
    ra.w = gelu_erf(__bfloat162float(ov.h[3]) * m1 + bt + xa.w);
    rb.x = gelu_erf(__bfloat162float(ov.h[4]) * m1 + bt + xb.x);
    rb.y = gelu_erf(__bfloat162float(ov.h[5]) * m1 + bt + xb.y);
    rb.z = gelu_erf(__bfloat162float(ov.h[6]) * m1 + bt + xb.z);
    rb.w = gelu_erf(__bfloat162float(ov.h[7]) * m1 + bt + xb.w);

    *(float4*)(out + e) = ra;
    *(float4*)(out + e + 4) = rb;
}

// ---------------- launcher ----------------
extern "C" void kernel_launch(void* const* d_in, const int* in_sizes, int n_in,
                              void* d_out, int out_size, void* d_ws, size_t ws_size,
                              hipStream_t stream)
{
    const float* x    = (const float*)d_in[0];
    const float* w3   = (const float*)d_in[1];
    const float* bn3w = (const float*)d_in[2];
    const float* bn3b = (const float*)d_in[3];
    const float* bn3m = (const float*)d_in[4];
    const float* bn3v = (const float*)d_in[5];
    const float* w5   = (const float*)d_in[6];
    const float* bn5w = (const float*)d_in[7];
    const float* bn5b = (const float*)d_in[8];
    const float* bn5m = (const float*)d_in[9];
    const float* bn5v = (const float*)d_in[10];
    const float* w7   = (const float*)d_in[11];
    const float* bn7w = (const float*)d_in[12];
    const float* bn7b = (const float*)d_in[13];
    const float* bn7m = (const float*)d_in[14];
    const float* bn7v = (const float*)d_in[15];
    const float* pww  = (const float*)d_in[16];
    const float* pbw  = (const float*)d_in[17];
    const float* pbb  = (const float*)d_in[18];
    const float* pbm  = (const float*)d_in[19];
    const float* pbv  = (const float*)d_in[20];
    const float* gga  = (const float*)d_in[21];
    const float* gbe  = (const float*)d_in[22];

    char* ws = (char*)d_ws;
    const size_t nelem = (size_t)BB * CC * HW;           // 33,554,432
    __hip_bfloat16* mid  = (__hip_bfloat16*)ws;                      // 64 MB
    __hip_bfloat16* out2 = (__hip_bfloat16*)(ws + nelem * 2);        // 64 MB
    __hip_bfloat16* pwb  = (__hip_bfloat16*)(ws + nelem * 4);        // 128 KB
    float* gx2 = (float*)(ws + nelem * 4 + 131072);                  // 32 KB
    float* nxb = (float*)(ws + nelem * 4 + 131072 + BB * CC * sizeof(float));

    hipMemsetAsync(gx2, 0, BB * CC * sizeof(float), stream);

    k_prep<<<CC * CC / 256, 256, 0, stream>>>(pww, pwb);
    k_dwconv<<<BB * CC, 256, 0, stream>>>(x, w3, bn3w, bn3b, bn3m, bn3v,
                                          w5, bn5w, bn5b, bn5m, bn5v,
                                          w7, bn7w, bn7b, bn7m, bn7v, mid);
    k_pw<<<BB * (HW / 64), 256, 0, stream>>>(mid, pwb, pbw, pbb, pbm, pbv, out2, gx2);
    k_grn<<<BB, 256, 0, stream>>>(gx2, nxb);
    k_final<<<(int)(nelem / (256 * 8)), 256, 0, stream>>>(out2, x, gga, gbe, nxb,
                                                          (float*)d_out);
}

// Round 3
// 525.013 us; speedup vs baseline: 1.1804x; 1.1804x over previous
//
#include <hip/hip_runtime.h>
#include <hip/hip_bf16.h>
#include <math.h>

#define BB 32
#define CC 256
#define HH 64
#define HW 4096

typedef __attribute__((ext_vector_type(8))) short short8;
typedef __attribute__((ext_vector_type(4))) float f32x4;

// fast tanh-form GELU: v*(1 - 1/(1+e^{2y})), y = 0.79788456*(v + 0.044715 v^3)
// 2y = v*(1.5957691216 + 0.0713548162 v^2)
__device__ __forceinline__ float gelu_fast(float v) {
    float u = v * __builtin_fmaf(0.0713548162f, v * v, 1.5957691216f);
    float e = __expf(u);                   // v_exp_f32 (+1 mul)
    return v - __fdividef(v, 1.0f + e);    // v_rcp + mul
}

// ---------------- Kernel 0: convert pw weights f32 -> bf16 ----------------
__global__ __launch_bounds__(256) void k_prep(const float* __restrict__ pw,
                                              __hip_bfloat16* __restrict__ pwb)
{
    const int i = blockIdx.x * 256 + threadIdx.x;   // 65536 total
    pwb[i] = __float2bfloat16(pw[i]);
}

// ---------------- Kernel 1: 3 depthwise convs + BN + GELU, averaged ----------------
// one block per (b,c) plane. lane = column (64 cols), 4 row-bands of 16 rows.
// Sliding 7x7 register window per thread; all 83 BN-scaled weights in VGPRs.
__global__ __launch_bounds__(256, 3) void k_dwconv(
    const float* __restrict__ x,
    const float* __restrict__ w3,
    const float* __restrict__ bn3w, const float* __restrict__ bn3b,
    const float* __restrict__ bn3m, const float* __restrict__ bn3v,
    const float* __restrict__ w5,
    const float* __restrict__ bn5w, const float* __restrict__ bn5b,
    const float* __restrict__ bn5m, const float* __restrict__ bn5v,
    const float* __restrict__ w7,
    const float* __restrict__ bn7w, const float* __restrict__ bn7b,
    const float* __restrict__ bn7m, const float* __restrict__ bn7v,
    __hip_bfloat16* __restrict__ mid)
{
    __shared__ float sm[70 * 70];
    __shared__ __align__(16) float wls[84];
    const int tid = threadIdx.x;
    const int blk = blockIdx.x;
    const int c = blk & 255;
    const int b = blk >> 8;
    const float* xp = x + ((size_t)(b * CC + c)) * HW;

    // BN affine params (uniform per block; every thread computes them)
    const float s3 = bn3w[c] * rsqrtf(bn3v[c] + 1e-5f);
    const float h3 = bn3b[c] - bn3m[c] * s3;
    const float s5 = bn5w[c] * rsqrtf(bn5v[c] + 1e-5f);
    const float h5 = bn5b[c] - bn5m[c] * s5;
    const float s7 = bn7w[c] * rsqrtf(bn7v[c] + 1e-5f);
    const float h7 = bn7b[c] - bn7m[c] * s7;

    // stage haloed 70x70 plane
    for (int i = tid; i < 4900; i += 256) {
        int r = i / 70, q = i - r * 70;
        int h = r - 3, w = q - 3;
        float v = 0.f;
        if ((unsigned)h < 64u && (unsigned)w < 64u) v = xp[h * 64 + w];
        sm[i] = v;
    }
    // stage BN-scaled weights: [0..8]=w3*s3, [9..33]=w5*s5, [34..82]=w7*s7
    if (tid < 9) wls[tid] = w3[c * 9 + tid] * s3;
    else if (tid < 34) wls[tid] = w5[c * 25 + tid - 9] * s5;
    else if (tid < 83) wls[tid] = w7[c * 49 + tid - 34] * s7;
    else if (tid == 83) wls[83] = 0.f;
    __syncthreads();

    // all 83 weights -> VGPRs via 21 float4 broadcast reads
    float wr[84];
#pragma unroll
    for (int i = 0; i < 21; ++i) {
        float4 q = *(const float4*)&wls[i * 4];
        wr[i * 4 + 0] = q.x; wr[i * 4 + 1] = q.y;
        wr[i * 4 + 2] = q.z; wr[i * 4 + 3] = q.w;
    }
    const float* w3r = &wr[0];
    const float* w5r = &wr[9];
    const float* w7r = &wr[34];

    const int col = tid & 63;
    const int rg = tid >> 6;         // 0..3
    const int r0 = rg * 16;          // first output row of this band

    // sliding window: slot j%7 holds input (halo) row r0+j, cols col..col+6
    float w[7][7];
#pragma unroll
    for (int j = 0; j < 6; ++j) {
        const float* srow = &sm[(r0 + j) * 70 + col];
#pragma unroll
        for (int d = 0; d < 7; ++d) w[j][d] = srow[d];
    }

    __hip_bfloat16* mp = mid + ((size_t)(b * CC + c)) * HW;

#pragma unroll
    for (int r = 0; r < 16; ++r) {
        {   // load incoming window row (input row r0+r+6) into slot (r+6)%7
            const float* srow = &sm[(r0 + r + 6) * 70 + col];
            float* wd = w[(r + 6) % 7];
#pragma unroll
            for (int d = 0; d < 7; ++d) wd[d] = srow[d];
        }
        float a7 = h7, a5 = h5, a3 = h3;
#pragma unroll
        for (int i = 0; i < 7; ++i) {
            const float* wrow = w[(r + i) % 7];
#pragma unroll
            for (int d = 0; d < 7; ++d) a7 = __builtin_fmaf(wrow[d], w7r[i * 7 + d], a7);
        }
#pragma unroll
        for (int i = 1; i <= 5; ++i) {
            const float* wrow = w[(r + i) % 7];
#pragma unroll
            for (int d = 1; d <= 5; ++d) a5 = __builtin_fmaf(wrow[d], w5r[(i - 1) * 5 + d - 1], a5);
        }
#pragma unroll
        for (int i = 2; i <= 4; ++i) {
            const float* wrow = w[(r + i) % 7];
#pragma unroll
            for (int d = 2; d <= 4; ++d) a3 = __builtin_fmaf(wrow[d], w3r[(i - 2) * 3 + d - 2], a3);
        }
        float v = (gelu_fast(a7) + gelu_fast(a5) + gelu_fast(a3)) * (1.0f / 3.0f);
        mp[(r0 + r) * 64 + col] = __float2bfloat16(v);
    }
}

// ---------------- Kernel 2: pointwise GEMM (MFMA bf16) + pwbn + sumsq ----------------
// block = (b, 64-hw tile) x all 256 output channels; 4 waves, each 16(hw) x 256(o)
#define ASTR 68   // LDS row stride (shorts) for A  [k=32][m=64]
#define BSTR 40   // LDS row stride (shorts) for B  [o=256][k=32]
__global__ __launch_bounds__(256) void k_pw(
    const __hip_bfloat16* __restrict__ mid,
    const __hip_bfloat16* __restrict__ pwb,
    const float* __restrict__ pbw, const float* __restrict__ pbb,
    const float* __restrict__ pbm, const float* __restrict__ pbv,
    __hip_bfloat16* __restrict__ out2,
    float* __restrict__ gx2)
{
    __shared__ __align__(16) short As[32 * ASTR];
    __shared__ __align__(16) short Bs[256 * BSTR];
    __shared__ float sc[256], sh[256], gxp[256];

    const int tid = threadIdx.x;
    const int blk = blockIdx.x;
    const int mt = blk & 63, b = blk >> 6;
    const int hw0 = mt * 64;

    {
        float s = pbw[tid] * rsqrtf(pbv[tid] + 1e-5f);
        sc[tid] = s;
        sh[tid] = pbb[tid] - pbm[tid] * s;
        gxp[tid] = 0.f;
    }

    const int wv = tid >> 6, lane = tid & 63;
    const int qd = lane >> 4, ln16 = lane & 15;

    f32x4 acc[16];
#pragma unroll
    for (int i = 0; i < 16; ++i) acc[i] = (f32x4){0.f, 0.f, 0.f, 0.f};

    const int ak = tid >> 3, am = tid & 7;
    const __hip_bfloat16* aptr = mid + ((size_t)(b * CC + ak)) * HW + hw0 + am * 8;
    const __hip_bfloat16* bptr = pwb + (size_t)tid * 256;

    for (int kk = 0; kk < 8; ++kk) {
        __syncthreads();
        // stage A tile: 32(k) x 64(m), k-major rows
        uint4 av = *(const uint4*)(aptr + (size_t)kk * 32 * HW);
        *(uint2*)&As[ak * ASTR + am * 8]     = make_uint2(av.x, av.y);
        *(uint2*)&As[ak * ASTR + am * 8 + 4] = make_uint2(av.z, av.w);
        // stage B tile: 256(o) x 32(k), row-major (k contiguous)
        const uint4* bp = (const uint4*)(bptr + kk * 32);
#pragma unroll
        for (int j = 0; j < 4; ++j) {
            *(uint4*)&Bs[tid * BSTR + j * 8] = bp[j];
        }
        __syncthreads();

        short8 af;
        const int mloc = wv * 16 + ln16;
#pragma unroll
        for (int j = 0; j < 8; ++j) af[j] = As[(qd * 8 + j) * ASTR + mloc];
#pragma unroll
        for (int nt = 0; nt < 16; ++nt) {
            short8 bf = *(short8*)&Bs[(nt * 16 + ln16) * BSTR + qd * 8];
            acc[nt] = __builtin_amdgcn_mfma_f32_16x16x32_bf16(af, bf, acc[nt], 0, 0, 0);
        }
    }

    // epilogue: pwbn affine, store bf16, per-channel sumsq reduction
    const size_t obase = ((size_t)b * CC) * HW + hw0 + wv * 16 + qd * 4;
#pragma unroll
    for (int nt = 0; nt < 16; ++nt) {
        const int o = nt * 16 + ln16;
        const float s = sc[o], h = sh[o];
        float v0 = acc[nt][0] * s + h;
        float v1 = acc[nt][1] * s + h;
        float v2 = acc[nt][2] * s + h;
        float v3 = acc[nt][3] * s + h;
        float p = v0 * v0 + v1 * v1 + v2 * v2 + v3 * v3;
        p += __shfl_xor(p, 16);
        p += __shfl_xor(p, 32);
        if ((lane & 48) == 0) atomicAdd(&gxp[o], p);
        __hip_bfloat16 ov[4];
        ov[0] = __float2bfloat16(v0);
        ov[1] = __float2bfloat16(v1);
        ov[2] = __float2bfloat16(v2);
        ov[3] = __float2bfloat16(v3);
        *(uint2*)&out2[obase + (size_t)o * HW] = *(uint2*)ov;
    }
    __syncthreads();
    atomicAdd(&gx2[b * CC + tid], gxp[tid]);
}

// ---------------- Kernel 3: GRN Nx = Gx / (mean_c Gx + eps) ----------------
__global__ __launch_bounds__(256) void k_grn(const float* __restrict__ gx2,
                                             float* __restrict__ nx)
{
    const int b = blockIdx.x, t = threadIdx.x;
    const float g = sqrtf(gx2[b * 256 + t]);
    float s = g;
#pragma unroll
    for (int m = 1; m <= 32; m <<= 1) s += __shfl_xor(s, m);
    __shared__ float ws4[4];
    if ((t & 63) == 0) ws4[t >> 6] = s;
    __syncthreads();
    const float tot = ws4[0] + ws4[1] + ws4[2] + ws4[3];
    const float mean = tot * (1.0f / 256.0f);
    nx[b * 256 + t] = g / (mean + 1e-6f);
}

// ---------------- Kernel 4: GRN apply + residual + GELU ----------------
__global__ __launch_bounds__(256) void k_final(
    const __hip_bfloat16* __restrict__ out2,
    const float* __restrict__ x,
    const float* __restrict__ gamma,
    const float* __restrict__ beta,
    const float* __restrict__ nx,
    float* __restrict__ out)
{
    const size_t e = ((size_t)blockIdx.x * 256 + threadIdx.x) * 8;
    const int bc = (int)(e >> 12);
    const int c = bc & 255;
    const float m1 = 1.0f + gamma[c] * nx[bc];
    const float bt = beta[c];

    union { uint4 u; __hip_bfloat16 h[8]; } ov;
    ov.u = *(const uint4*)(out2 + e);
    float4 xa = *(const float4*)(x + e);
    float4 xb = *(const float4*)(x + e + 4);

    float4 ra, rb;
    ra.x = gelu_fast(__bfloat162float(ov.h[0]) * m1 + bt + xa.x);
    ra.y = gelu_fast(__bfloat162float(ov.h[1]) * m1 + bt + xa.y);
    ra.z = gelu_fast(__bfloat162float(ov.h[2]) * m1 + bt + xa.z);
    ra.w = gelu_fast(__bfloat162float(ov.h[3]) * m1 + bt + xa.w);
    rb.x = gelu_fast(__bfloat162float(ov.h[4]) * m1 + bt + xb.x);
    rb.y = gelu_fast(__bfloat162float(ov.h[5]) * m1 + bt + xb.y);
    rb.z = gelu_fast(__bfloat162float(ov.h[6]) * m1 + bt + xb.z);
    rb.w = gelu_fast(__bfloat162float(ov.h[7]) * m1 + bt + xb.w);

    *(float4*)(out + e) = ra;
    *(float4*)(out + e + 4) = rb;
}

// ---------------- launcher ----------------
extern "C" void kernel_launch(void* const* d_in, const int* in_sizes, int n_in,
                              void* d_out, int out_size, void* d_ws, size_t ws_size,
                              hipStream_t stream)
{
    const float* x    = (const float*)d_in[0];
    const float* w3   = (const float*)d_in[1];
    const float* bn3w = (const float*)d_in[2];
    const float* bn3b = (const float*)d_in[3];
    const float* bn3m = (const float*)d_in[4];
    const float* bn3v = (const float*)d_in[5];
    const float* w5   = (const float*)d_in[6];
    const float* bn5w = (const float*)d_in[7];
    const float* bn5b = (const float*)d_in[8];
    const float* bn5m = (const float*)d_in[9];
    const float* bn5v = (const float*)d_in[10];
    const float* w7   = (const float*)d_in[11];
    const float* bn7w = (const float*)d_in[12];
    const float* bn7b = (const float*)d_in[13];
    const float* bn7m = (const float*)d_in[14];
    const float* bn7v = (const float*)d_in[15];
    const float* pww  = (const float*)d_in[16];
    const float* pbw  = (const float*)d_in[17];
    const float* pbb  = (const float*)d_in[18];
    const float* pbm  = (const float*)d_in[19];
    const float* pbv  = (const float*)d_in[20];
    const float* gga  = (const float*)d_in[21];
    const float* gbe  = (const float*)d_in[22];

    char* ws = (char*)d_ws;
    const size_t nelem = (size_t)BB * CC * HW;           // 33,554,432
    __hip_bfloat16* mid  = (__hip_bfloat16*)ws;                      // 64 MB
    __hip_bfloat16* out2 = (__hip_bfloat16*)(ws + nelem * 2);        // 64 MB
    __hip_bfloat16* pwb  = (__hip_bfloat16*)(ws + nelem * 4);        // 128 KB
    float* gx2 = (float*)(ws + nelem * 4 + 131072);                  // 32 KB
    float* nxb = (float*)(ws + nelem * 4 + 131072 + BB * CC * sizeof(float));

    hipMemsetAsync(gx2, 0, BB * CC * sizeof(float), stream);

    k_prep<<<CC * CC / 256, 256, 0, stream>>>(pww, pwb);
    k_dwconv<<<BB * CC, 256, 0, stream>>>(x, w3, bn3w, bn3b, bn3m, bn3v,
                                          w5, bn5w, bn5b, bn5m, bn5v,
                                          w7, bn7w, bn7b, bn7m, bn7v, mid);
    k_pw<<<BB * (HW / 64), 256, 0, stream>>>(mid, pwb, pbw, pbb, pbm, pbv, out2, gx2);
    k_grn<<<BB, 256, 0, stream>>>(gx2, nxb);
    k_final<<<(int)(nelem / (256 * 8)), 256, 0, stream>>>(out2, x, gga, gbe, nxb,
                                                          (float*)d_out);
}